// Round 5
// baseline (819.132 us; speedup 1.0000x reference)
//
#include <hip/hip_runtime.h>
#include <math.h>

// Problem constants
constexpr int NB = 32, ND = 512, NHID = 512, NSTEPS = 31;
constexpr int NC5 = 2560;          // 5H
constexpr int BH = NB * NHID;      // 16384
constexpr int HSLOT_Z = 32;        // zero slot id

constexpr float INV2048 = 1.f / 2048.f;

typedef _Float16 half8  __attribute__((ext_vector_type(8)));
typedef _Float16 half4  __attribute__((ext_vector_type(4)));
typedef float    f32x16 __attribute__((ext_vector_type(16)));
typedef unsigned long long u64;

// ---------------- workspace layout (float offsets) ----------------
// h-state slots WRITE-ONCE: 0..31 leaves, 32 zero, 33+step fresh (<=63).
// graw slot 31 = dummy for padded pairs.
constexpr size_t OFF_GRAW = 0;                                     // [32][32][2560]
constexpr size_t OFF_PNH  = OFF_GRAW + (size_t)32 * 32 * 2560;     // [31][32][512]
constexpr size_t OFF_PNC  = OFF_PNH + (size_t)31 * 32 * 512;
constexpr size_t OFF_PLOG = OFF_PNC + (size_t)31 * 32 * 512;       // [32][32] f32
constexpr size_t OFF_CST  = OFF_PLOG + 1024;                       // [33][32][512]
constexpr size_t OFF_HHI  = OFF_CST + (size_t)33 * 32 * 512;       // halves [64][32][512]
constexpr size_t OFF_HLO  = OFF_HHI + (size_t)64 * 32 * 512 / 2;
constexpr size_t OFF_WTH  = OFF_HLO + (size_t)64 * 32 * 512 / 2;   // W^T hi [n][k]
constexpr size_t OFF_WTL  = OFF_WTH + (size_t)NC5 * 1024 / 2;
constexpr size_t OFF_INT  = OFF_WTL + (size_t)NC5 * 1024 / 2;      // 8192 ints
constexpr size_t OFF_LIST = OFF_INT + 8192;                        // u64 elist64[64]

// int region: counters + bookkeeping + static step0 list
constexpr int IR_GD    = 0;        // stripes at 0,32,64,96 (zeroed every launch)
constexpr int IR_PIDX  = 1024;     // [32][32]
constexpr int IR_HIDX  = 2048;     // [32][32]
constexpr int IR_CIDX  = 3072;     // [32][32]
constexpr int IR_PREVK = 4096;     // [32]
constexpr int IR_E0    = 5120;     // unsigned elist0[992]

__device__ __forceinline__ float sigf(float x) { return 1.f / (1.f + expf(-x)); }

// device-scope (L2-bypassing) helpers — used ONLY for intra-dispatch payloads
__device__ __forceinline__ int ld_sc(const int* p) {
    return __hip_atomic_load(p, __ATOMIC_RELAXED, __HIP_MEMORY_SCOPE_AGENT);
}
__device__ __forceinline__ u64 ld_sc64(const void* p) {
    return __hip_atomic_load((const u64*)p, __ATOMIC_RELAXED, __HIP_MEMORY_SCOPE_AGENT);
}
__device__ __forceinline__ void st_sc64(void* p, u64 v) {
    __hip_atomic_store((u64*)p, v, __ATOMIC_RELAXED, __HIP_MEMORY_SCOPE_AGENT);
}
// entry pack: bits0-4 batch, 5-9 pair-slot (31=dummy), 10-15 left h, 16-21 right h
__device__ __forceinline__ unsigned pack_e(int b, int slot, int l, int r) {
    return (unsigned)b | ((unsigned)slot << 5) | ((unsigned)l << 10) | ((unsigned)r << 16);
}

// ---------------- init: bookkeeping, step-0 list, zero slot, counters ----------------
__global__ __launch_bounds__(256) void init_kernel(
    int* __restrict__ ireg,
    _Float16* __restrict__ hHi, _Float16* __restrict__ hLo, float* __restrict__ cSt)
{
    const int blk = blockIdx.x, tid = threadIdx.x;
    if (blk < 32) {
        if (tid < 32) {
            ireg[IR_PIDX + blk * 32 + tid] = min(tid, 30);
            ireg[IR_HIDX + blk * 32 + tid] = tid;
            ireg[IR_CIDX + blk * 32 + tid] = tid;
        }
        if (tid == 0) ireg[IR_PREVK + blk] = -1;
        if (tid < 31)
            ireg[IR_E0 + tid * 32 + blk] = (int)pack_e(blk, tid, tid, tid + 1);
    } else if (blk == 32) {
        const size_t zb = (size_t)HSLOT_Z * NB * NHID;
        for (int i = tid; i < NB * NHID; i += 256) {
            hHi[zb + i] = (_Float16)0.f;
            hLo[zb + i] = (_Float16)0.f;
            cSt[zb + i] = 0.f;
        }
    } else {
        if (tid < 128) ireg[IR_GD + tid] = 0;
    }
}

// ---------------- W_comp -> transposed split fp16 planes ----------------
__global__ __launch_bounds__(256) void wsplit_kernel(
    const float* __restrict__ W, _Float16* __restrict__ Wth, _Float16* __restrict__ Wtl)
{
    __shared__ float t[32][33];
    const int n0 = blockIdx.x * 32, k0 = blockIdx.y * 32;
    const int tid = threadIdx.x;
    const int c = tid & 31, r8 = tid >> 5;
#pragma unroll
    for (int p = 0; p < 4; ++p) {
        int r = p * 8 + r8;
        t[r][c] = W[(size_t)(k0 + r) * NC5 + n0 + c];
    }
    __syncthreads();
    const int nl = tid >> 3, k4 = (tid & 7) * 4;
    half4 vh, vl;
#pragma unroll
    for (int i = 0; i < 4; ++i) {
        float v = t[k4 + i][nl];
        _Float16 hh = (_Float16)v;
        vh[i] = hh;
        vl[i] = (_Float16)((v - (float)hh) * 2048.f);
    }
    size_t o = (size_t)(n0 + nl) * 1024 + k0 + k4;
    *(half4*)&Wth[o] = vh;
    *(half4*)&Wtl[o] = vl;
}

// ---------------- word GEMM: leaves -> state slots 0..31 ----------------
__global__ __launch_bounds__(256) void word_gemm64(
    const float* __restrict__ A, const float* __restrict__ W,
    const float* __restrict__ bias,
    _Float16* __restrict__ hi0, _Float16* __restrict__ lo0,
    float* __restrict__ cst, float* __restrict__ out)
{
    const int m0 = blockIdx.x * 64;
    const int n0 = blockIdx.y * 64;
    const int tid = threadIdx.x;
    const int tx = tid & 15, ty = tid >> 4;
    __shared__ float As[16][64];
    __shared__ float Bs[16][64];
    float acc[4][4];
#pragma unroll
    for (int i = 0; i < 4; ++i)
#pragma unroll
        for (int j = 0; j < 4; ++j) acc[i][j] = 0.f;

    for (int kt = 0; kt < ND; kt += 16) {
        {
            int row = tid >> 2, kq = tid & 3;
            float4 v = *(const float4*)(A + (size_t)(m0 + row) * ND + kt + kq * 4);
            As[kq * 4 + 0][row] = v.x;
            As[kq * 4 + 1][row] = v.y;
            As[kq * 4 + 2][row] = v.z;
            As[kq * 4 + 3][row] = v.w;
            int kr = tid >> 4, nq = tid & 15;
            float4 vb = *(const float4*)(W + (size_t)(kt + kr) * 1024 + n0 + nq * 4);
            *(float4*)&Bs[kr][nq * 4] = vb;
        }
        __syncthreads();
#pragma unroll
        for (int kk = 0; kk < 16; ++kk) {
            float a0 = As[kk][ty * 4 + 0], a1 = As[kk][ty * 4 + 1];
            float a2 = As[kk][ty * 4 + 2], a3 = As[kk][ty * 4 + 3];
            float4 bv = *(float4*)&Bs[kk][tx * 4];
            acc[0][0] = fmaf(a0, bv.x, acc[0][0]); acc[0][1] = fmaf(a0, bv.y, acc[0][1]);
            acc[0][2] = fmaf(a0, bv.z, acc[0][2]); acc[0][3] = fmaf(a0, bv.w, acc[0][3]);
            acc[1][0] = fmaf(a1, bv.x, acc[1][0]); acc[1][1] = fmaf(a1, bv.y, acc[1][1]);
            acc[1][2] = fmaf(a1, bv.z, acc[1][2]); acc[1][3] = fmaf(a1, bv.w, acc[1][3]);
            acc[2][0] = fmaf(a2, bv.x, acc[2][0]); acc[2][1] = fmaf(a2, bv.y, acc[2][1]);
            acc[2][2] = fmaf(a2, bv.z, acc[2][2]); acc[2][3] = fmaf(a2, bv.w, acc[2][3]);
            acc[3][0] = fmaf(a3, bv.x, acc[3][0]); acc[3][1] = fmaf(a3, bv.y, acc[3][1]);
            acc[3][2] = fmaf(a3, bv.z, acc[3][2]); acc[3][3] = fmaf(a3, bv.w, acc[3][3]);
        }
        __syncthreads();
    }
    float* nodes = out + 2 * BH;
#pragma unroll
    for (int i = 0; i < 4; ++i) {
        int r = m0 + ty * 4 + i;
        int b = r >> 5, l = r & 31;
#pragma unroll
        for (int jn = 0; jn < 4; ++jn) {
            int n = n0 + tx * 4 + jn;
            float v = acc[i][jn] + bias[n];
            if (n < NHID) {
                size_t si = ((size_t)l * NB + b) * NHID + n;
                _Float16 hh = (_Float16)v;
                hi0[si] = hh;
                lo0[si] = (_Float16)((v - (float)hh) * 2048.f);
                nodes[((size_t)b * 63 + l) * NHID + n] = v;
            } else {
                cst[((size_t)l * NB + b) * NHID + (n - NHID)] = v;
            }
        }
    }
}

// ---------------- step-0 pair GEMM: 992 pairs, B-reuse grid ----------------
// grid (80 cols, 4 row-groups); each block holds its 32-col B panel in VGPRs
// and loops 7-8 row tiles. graw written with plain cached stores (published
// by the kernel boundary).
__global__ __launch_bounds__(256, 1) void pair_gemm0(
    const _Float16* __restrict__ hHi, const _Float16* __restrict__ hLo,
    const _Float16* __restrict__ Wth, const _Float16* __restrict__ Wtl,
    const int* __restrict__ ireg, float* __restrict__ graw)
{
    const int col = blockIdx.x, g = blockIdx.y;
    const int tid = threadIdx.x;
    const int kw = tid >> 6, lane = tid & 63;
    const int l5 = lane >> 5, ln = lane & 31;
    __shared__ float red[4][32][32];
    __shared__ unsigned s_entry[32];

    const _Float16* bHiP = Wth + (size_t)(col * 32 + ln) * 1024 + (kw << 8) + l5 * 8;
    const _Float16* bLoP = Wtl + (size_t)(col * 32 + ln) * 1024 + (kw << 8) + l5 * 8;
    half8 Bh[16], Bl[16];
#pragma unroll
    for (int ks = 0; ks < 16; ++ks) {
        Bh[ks] = *(const half8*)(bHiP + ks * 16);
        Bl[ks] = *(const half8*)(bLoP + ks * 16);
    }

    const int mt0 = g * 8, mt1 = min(mt0 + 8, 31);
    for (int mt = mt0; mt < mt1; ++mt) {
        if (tid < 32) s_entry[tid] = (unsigned)ireg[IR_E0 + mt * 32 + tid];
        __syncthreads();
        {
            const unsigned e = s_entry[ln];
            const int db = e & 31;
            const int lsl = (e >> 10) & 63, rsl = (e >> 16) & 63;
            const int hs = (kw < 2) ? lsl : rsl;
            const int koff = ((kw & 1) << 8) + l5 * 8;
            const _Float16* aHiP = hHi + ((size_t)hs * NB + db) * NHID + koff;
            const _Float16* aLoP = hLo + ((size_t)hs * NB + db) * NHID + koff;
            f32x16 acc1 = (f32x16)0.f, acc2 = (f32x16)0.f;
#pragma unroll
            for (int ks = 0; ks < 16; ++ks) {
                half8 Ah = *(const half8*)(aHiP + ks * 16);
                half8 Al = *(const half8*)(aLoP + ks * 16);
                acc1 = __builtin_amdgcn_mfma_f32_32x32x16_f16(Ah, Bh[ks], acc1, 0, 0, 0);
                acc2 = __builtin_amdgcn_mfma_f32_32x32x16_f16(Ah, Bl[ks], acc2, 0, 0, 0);
                acc2 = __builtin_amdgcn_mfma_f32_32x32x16_f16(Al, Bh[ks], acc2, 0, 0, 0);
            }
#pragma unroll
            for (int a = 0; a < 16; ++a) {
                int row = (a & 3) + 8 * (a >> 2) + 4 * l5;
                red[kw][row][ln] = acc1[a] + acc2[a] * INV2048;
            }
        }
        __syncthreads();
        {
            const int row = tid >> 3, c0 = (tid & 7) * 4;
            const unsigned er = s_entry[row];
            const int rb = er & 31, rslot = (er >> 5) & 31;
            float4 s;
            s.x = (red[0][row][c0+0] + red[1][row][c0+0]) + (red[2][row][c0+0] + red[3][row][c0+0]);
            s.y = (red[0][row][c0+1] + red[1][row][c0+1]) + (red[2][row][c0+1] + red[3][row][c0+1]);
            s.z = (red[0][row][c0+2] + red[1][row][c0+2]) + (red[2][row][c0+2] + red[3][row][c0+2]);
            s.w = (red[0][row][c0+3] + red[1][row][c0+3]) + (red[2][row][c0+3] + red[3][row][c0+3]);
            *(float4*)&graw[((size_t)rslot * NB + rb) * NC5 + col * 32 + c0] = s;
        }
        __syncthreads();
    }
}

// ---------------- per-step kernel: update(step) then GEMM(step+1) ----------------
// 80 blocks. Blocks 0..31: update batch nt (graw from PREVIOUS dispatch, plain
// cached). They publish fresh h (sc), next-pair entries (sc), bump striped
// counters. Then ALL 80 blocks GEMM step+1's 64 fresh rows; graw written with
// plain stores (published by kernel boundary). Last step: update only.
__global__ __launch_bounds__(256, 1) void step_kernel(
    _Float16* __restrict__ hHi, _Float16* __restrict__ hLo,
    const _Float16* __restrict__ Wth, const _Float16* __restrict__ Wtl,
    float* __restrict__ graw, const float* __restrict__ bias,
    const float* __restrict__ q, const int* __restrict__ len,
    float* __restrict__ pnh, float* __restrict__ pnc, float* __restrict__ plogG,
    float* __restrict__ cSt, u64* __restrict__ elist64,
    int* __restrict__ ireg, float* __restrict__ out, int step)
{
    const int nt = blockIdx.x;
    const int tid = threadIdx.x;
    const int kw = tid >> 6, lane = tid & 63;
    const int l5 = lane >> 5, ln = lane & 31;
    const int last = (step == NSTEPS - 1);

    int* gd = ireg + IR_GD;

    __shared__ float red[4][32][32];
    __shared__ unsigned s_entry[64];
    __shared__ int s_pidx[32], s_hidx[32], s_cidx[32];
    __shared__ int s_k, s_prevk;

    if (nt < NB) {
        // ================= UPDATE role: batch b = nt =================
        const int b = nt;
        if (tid < 32) {
            s_pidx[tid] = ireg[IR_PIDX + b * 32 + tid];
            s_hidx[tid] = ireg[IR_HIDX + b * 32 + tid];
            s_cidx[tid] = ireg[IR_CIDX + b * 32 + tid];
        }
        if (tid == 0) s_prevk = ireg[IR_PREVK + b];
        const int lenb = len[b];
        __syncthreads();

        const int pk = s_prevk;
        int nf;
        if (step == 0) nf = 31; else if (pk < 0) nf = 0; else nf = (pk >= 1) ? 2 : 1;

        // Phase A: activate fresh pairs — one pair per wave, plain cached graw
        for (int f = kw; f < nf; f += 4) {
            const int j = (step == 0) ? f : (pk - (nf - 1) + f);
            const int slot = s_pidx[j];
            const int lc = s_cidx[j], rc2 = s_cidx[j + 1];
            const float* gr  = graw + ((size_t)slot * NB + b) * NC5;
            const float* clp = cSt + ((size_t)lc * NB + b) * NHID;
            const float* crp = cSt + ((size_t)rc2 * NB + b) * NHID;
            float lpart = 0.f;
#pragma unroll
            for (int i = 0; i < 2; ++i) {
                const int h = 4 * lane + 256 * i;
                float4 g0 = *(const float4*)(gr + h);
                float4 g1 = *(const float4*)(gr + 512 + h);
                float4 g2 = *(const float4*)(gr + 1024 + h);
                float4 g3 = *(const float4*)(gr + 1536 + h);
                float4 g4 = *(const float4*)(gr + 2048 + h);
                const float4 b0 = *(const float4*)(bias + h);
                const float4 b1 = *(const float4*)(bias + 512 + h);
                const float4 b2 = *(const float4*)(bias + 1024 + h);
                const float4 b3 = *(const float4*)(bias + 1536 + h);
                const float4 b4 = *(const float4*)(bias + 2048 + h);
                const float4 cl4 = *(const float4*)(clp + h);
                const float4 cr4 = *(const float4*)(crp + h);
                const float4 q4  = *(const float4*)(q + h);
                float4 hv, cv;
#define CELL(e) { \
                float c = cl4.e * sigf(g1.e + b1.e + 1.f) + cr4.e * sigf(g2.e + b2.e + 1.f) \
                        + tanhf(g3.e + b3.e) * sigf(g0.e + b0.e); \
                float hh = sigf(g4.e + b4.e) * tanhf(c); \
                cv.e = c; hv.e = hh; lpart = fmaf(hh, q4.e, lpart); }
                CELL(x) CELL(y) CELL(z) CELL(w)
#undef CELL
                const size_t po = ((size_t)slot * NB + b) * NHID + h;
                *(float4*)(pnh + po) = hv;
                *(float4*)(pnc + po) = cv;
            }
#pragma unroll
            for (int off = 32; off > 0; off >>= 1) lpart += __shfl_down(lpart, off);
            if (lane == 0) plogG[b * 32 + slot] = lpart;
        }
        __syncthreads();

        // Phase B: argmax over j < actb (first-index tie-break)
        const int actb = lenb - 1 - step;
        const int merge = actb >= 1;
        if (tid < 64) {
            float v = -1e30f;
            int idx = tid;
            if (tid < actb && tid < 31) v = plogG[b * 32 + s_pidx[tid]];
#pragma unroll
            for (int off = 32; off > 0; off >>= 1) {
                float ov = __shfl_down(v, off);
                int   oi = __shfl_down(idx, off);
                if (ov > v || (ov == v && oi < idx)) { v = ov; idx = oi; }
            }
            if (tid == 0) s_k = idx;
        }
        __syncthreads();
        const int k = s_k;
        const int NSLOT = 33 + step;

        // Phase C: node output, fresh h write (sc), final hf/cf
        float* noderow = out + 2 * BH + ((size_t)b * 63 + 32 + step) * NHID;
        if (merge) {
            const int kslot = s_pidx[k];
            const int csl = s_cidx[k];
            if (tid < 128) {
                const int h0 = tid * 4;
                const size_t pb = ((size_t)kslot * NB + b) * NHID + h0;
                float4 x4 = *(const float4*)&pnh[pb];
                float4 c4 = *(const float4*)&pnc[pb];
                half4 hv, lv;
#pragma unroll
                for (int i = 0; i < 4; ++i) {
                    float x = (&x4.x)[i];
                    _Float16 hh = (_Float16)x;
                    hv[i] = hh;
                    lv[i] = (_Float16)((x - (float)hh) * 2048.f);
                }
                const size_t so = ((size_t)NSLOT * NB + b) * NHID + h0;
                st_sc64(&hHi[so], __builtin_bit_cast(u64, hv));
                st_sc64(&hLo[so], __builtin_bit_cast(u64, lv));
                *(float4*)&cSt[((size_t)csl * NB + b) * NHID + h0] = c4;
                *(float4*)&noderow[h0] = x4;
                if (last) {
                    *(float4*)&out[b * NHID + h0] = x4;
                    *(float4*)&out[BH + b * NHID + h0] = c4;
                }
            }
        } else {
            const int s0p = s_pidx[0], s0h = s_hidx[0], s0c = s_cidx[0];
            if (tid < 128) {
                const int h0 = tid * 4;
                if (!last) {
                    *(float4*)&noderow[h0] =
                        *(const float4*)&pnh[((size_t)s0p * NB + b) * NHID + h0];
                } else {
                    const size_t so = ((size_t)s0h * NB + b) * NHID + h0;
                    half4 hv = *(const half4*)&hHi[so];   // written in earlier dispatch
                    half4 lv = *(const half4*)&hLo[so];
                    float4 x4;
#pragma unroll
                    for (int i = 0; i < 4; ++i)
                        (&x4.x)[i] = (float)hv[i] + (float)lv[i] * INV2048;
                    *(float4*)&noderow[h0] = x4;
                    *(float4*)&out[b * NHID + h0] = x4;
                    *(float4*)&out[BH + b * NHID + h0] =
                        *(const float4*)&cSt[((size_t)s0c * NB + b) * NHID + h0];
                }
            }
        }
        __syncthreads();   // drains each wave's stores (incl. sc h-stores)

        // Phase D: publish stamped entries (sc), shift bookkeeping
        if (tid == 0) {
            const unsigned dummy = pack_e(b, 31, HSLOT_Z, HSLOT_Z);
            if (merge) {
                unsigned e1 = pack_e(b, s_pidx[k], NSLOT,
                                     (k + 2 <= 31) ? s_hidx[k + 2] : HSLOT_Z);
                unsigned e0 = (k >= 1)
                    ? pack_e(b, s_pidx[k - 1], s_hidx[k - 1], NSLOT) : dummy;
                if (!last) {
                    st_sc64(&elist64[2 * b],     (u64)e0);
                    st_sc64(&elist64[2 * b + 1], (u64)e1);
                }
                const int recycP = s_pidx[k + 1];
                for (int j2 = k + 1; j2 <= 29; ++j2) s_pidx[j2] = s_pidx[j2 + 1];
                if (k < 30) s_pidx[30] = recycP;
                s_hidx[k] = NSLOT;
                for (int pp = k + 1; pp <= 30; ++pp) s_hidx[pp] = s_hidx[pp + 1];
                s_hidx[31] = HSLOT_Z;
                for (int pp = k + 1; pp <= 30; ++pp) s_cidx[pp] = s_cidx[pp + 1];
                s_cidx[31] = HSLOT_Z;
                s_prevk = k;
            } else {
                if (!last) {
                    st_sc64(&elist64[2 * b],     (u64)dummy);
                    st_sc64(&elist64[2 * b + 1], (u64)dummy);
                }
                s_prevk = -1;
            }
        }
        __syncthreads();
        if (tid < 32) {
            ireg[IR_PIDX + b * 32 + tid] = s_pidx[tid];
            ireg[IR_HIDX + b * 32 + tid] = s_hidx[tid];
            ireg[IR_CIDX + b * 32 + tid] = s_cidx[tid];
        }
        if (tid == 0) {
            ireg[IR_PREVK + b] = s_prevk;
            if (!last) {
                asm volatile("s_waitcnt vmcnt(0)" ::: "memory");
                __hip_atomic_fetch_add(&gd[(b & 3) * 32], 1, __ATOMIC_RELAXED,
                                       __HIP_MEMORY_SCOPE_AGENT);
            }
        }
    }

    if (last) return;

    // ================= GEMM role: col = nt, step+1's 64 fresh rows =================
    const int col = nt;
    const _Float16* bHiP = Wth + (size_t)(col * 32 + ln) * 1024 + (kw << 8) + l5 * 8;
    const _Float16* bLoP = Wtl + (size_t)(col * 32 + ln) * 1024 + (kw << 8) + l5 * 8;
    half8 Bh[16], Bl[16];
#pragma unroll
    for (int ks = 0; ks < 16; ++ks) {
        Bh[ks] = *(const half8*)(bHiP + ks * 16);
        Bl[ks] = *(const half8*)(bLoP + ks * 16);
    }

    // wait for all 32 update arrivals (cumulative striped counters)
    if (tid < 4) {
        const int tgt = 8 * (step + 1);
        while (ld_sc(&gd[tid * 32]) < tgt) __builtin_amdgcn_s_sleep(1);
    }
    __syncthreads();
    if (tid < 64) s_entry[tid] = (unsigned)ld_sc64(&elist64[tid]);
    __syncthreads();

#pragma unroll
    for (int half = 0; half < 2; ++half) {
        const unsigned* se = s_entry + half * 32;
        {
            const unsigned e = se[ln];
            const int db = e & 31;
            const int lsl = (e >> 10) & 63, rsl = (e >> 16) & 63;
            const int hs = (kw < 2) ? lsl : rsl;
            const int koff = ((kw & 1) << 8) + l5 * 8;
            const _Float16* aHiP = hHi + ((size_t)hs * NB + db) * NHID + koff;
            const _Float16* aLoP = hLo + ((size_t)hs * NB + db) * NHID + koff;
            f32x16 acc1 = (f32x16)0.f, acc2 = (f32x16)0.f;
#pragma unroll
            for (int ks = 0; ks < 16; ++ks) {
                half8 Ah = *(const half8*)(aHiP + ks * 16);
                half8 Al = *(const half8*)(aLoP + ks * 16);
                acc1 = __builtin_amdgcn_mfma_f32_32x32x16_f16(Ah, Bh[ks], acc1, 0, 0, 0);
                acc2 = __builtin_amdgcn_mfma_f32_32x32x16_f16(Ah, Bl[ks], acc2, 0, 0, 0);
                acc2 = __builtin_amdgcn_mfma_f32_32x32x16_f16(Al, Bh[ks], acc2, 0, 0, 0);
            }
#pragma unroll
            for (int a = 0; a < 16; ++a) {
                int row = (a & 3) + 8 * (a >> 2) + 4 * l5;
                red[kw][row][ln] = acc1[a] + acc2[a] * INV2048;
            }
        }
        __syncthreads();
        {
            const int row = tid >> 3, c0 = (tid & 7) * 4;
            const unsigned er = se[row];
            const int rb = er & 31, rslot = (er >> 5) & 31;
            float4 s;
            s.x = (red[0][row][c0+0] + red[1][row][c0+0]) + (red[2][row][c0+0] + red[3][row][c0+0]);
            s.y = (red[0][row][c0+1] + red[1][row][c0+1]) + (red[2][row][c0+1] + red[3][row][c0+1]);
            s.z = (red[0][row][c0+2] + red[1][row][c0+2]) + (red[2][row][c0+2] + red[3][row][c0+2]);
            s.w = (red[0][row][c0+3] + red[1][row][c0+3]) + (red[2][row][c0+3] + red[3][row][c0+3]);
            *(float4*)&graw[((size_t)rslot * NB + rb) * NC5 + col * 32 + c0] = s;
        }
        __syncthreads();
    }
}

extern "C" void kernel_launch(void* const* d_in, const int* in_sizes, int n_in,
                              void* d_out, int out_size, void* d_ws, size_t ws_size,
                              hipStream_t stream) {
    const float* inp    = (const float*)d_in[0];
    const int*   length = (const int*)d_in[1];
    const float* W_word = (const float*)d_in[2];
    const float* b_word = (const float*)d_in[3];
    const float* W_comp = (const float*)d_in[4];
    const float* b_comp = (const float*)d_in[5];
    const float* q      = (const float*)d_in[6];
    float* out = (float*)d_out;
    float* ws  = (float*)d_ws;

    float*     graw = ws + OFF_GRAW;
    float*     pnh  = ws + OFF_PNH;
    float*     pnc  = ws + OFF_PNC;
    float*     plog = ws + OFF_PLOG;
    float*     cSt  = ws + OFF_CST;
    _Float16*  hHi  = (_Float16*)(ws + OFF_HHI);
    _Float16*  hLo  = (_Float16*)(ws + OFF_HLO);
    _Float16*  Wth  = (_Float16*)(ws + OFF_WTH);
    _Float16*  Wtl  = (_Float16*)(ws + OFF_WTL);
    int*       ireg = (int*)(ws + OFF_INT);
    u64*       elist64 = (u64*)(ws + OFF_LIST);

    init_kernel<<<34, 256, 0, stream>>>(ireg, hHi, hLo, cSt);
    wsplit_kernel<<<dim3(NC5 / 32, 1024 / 32), 256, 0, stream>>>(W_comp, Wth, Wtl);
    word_gemm64<<<dim3(16, 16), 256, 0, stream>>>(inp, W_word, b_word,
                                                  hHi, hLo, cSt, out);
    pair_gemm0<<<dim3(80, 4), 256, 0, stream>>>(hHi, hLo, Wth, Wtl, ireg, graw);
    for (int i = 0; i < NSTEPS; ++i) {
        const int grid = (i == NSTEPS - 1) ? 32 : 80;
        step_kernel<<<grid, 256, 0, stream>>>(
            hHi, hLo, Wth, Wtl, graw, b_comp, q, length,
            pnh, pnc, plog, cSt, elist64, ireg, out, i);
    }
}

// Round 6
// 719.551 us; speedup vs baseline: 1.1384x; 1.1384x over previous
//
#include <hip/hip_runtime.h>
#include <math.h>

// Problem constants
constexpr int NB = 32, ND = 512, NHID = 512, NSTEPS = 31;
constexpr int NC5 = 2560;          // 5H
constexpr int BH = NB * NHID;      // 16384
constexpr int HSLOT_Z = 32;        // zero slot id
constexpr int NROW0 = 992;         // step-0 graw rows
constexpr int NGEMM = 80;
constexpr int NBLK = 160;          // 80 GEMM + 32 update + 48 step0-only

constexpr float INV2048 = 1.f / 2048.f;

typedef _Float16 half8  __attribute__((ext_vector_type(8)));
typedef _Float16 half4  __attribute__((ext_vector_type(4)));
typedef float    f32x16 __attribute__((ext_vector_type(16)));
typedef unsigned long long u64;

// ---------------- workspace layout (float offsets) ----------------
// WRITE-ONCE regions (enable plain cached consumer loads):
//   graw rows: step0 = rows 0..991 (row = pair*32 + b), step s>=1 = rows
//              992+(s-1)*64 .. +63 (row = list position). Never recycled.
//   h-state slots: 0..31 leaves, 32 zero, 33+step fresh.
//   elist: [31][64] stamped entries, step-indexed.
constexpr size_t OFF_GRAW = 0;                                     // [2912][2560]
constexpr size_t OFF_PNH  = OFF_GRAW + (size_t)2912 * 2560;        // [31][32][512]
constexpr size_t OFF_PNC  = OFF_PNH + (size_t)31 * 32 * 512;
constexpr size_t OFF_CST  = OFF_PNC + (size_t)31 * 32 * 512;       // [33][32][512]
constexpr size_t OFF_HHI  = OFF_CST + (size_t)33 * 32 * 512;       // halves [64][32][512]
constexpr size_t OFF_HLO  = OFF_HHI + (size_t)64 * 32 * 512 / 2;
constexpr size_t OFF_WTH  = OFF_HLO + (size_t)64 * 32 * 512 / 2;   // W^T hi [n][k]
constexpr size_t OFF_WTL  = OFF_WTH + (size_t)NC5 * 1024 / 2;
constexpr size_t OFF_INT  = OFF_WTL + (size_t)NC5 * 1024 / 2;      // 8192 ints
constexpr size_t OFF_LIST = OFF_INT + 8192;                        // u64[31*64]

// int region
constexpr int IR_GD = 0;           // GEMM-arrival stripes at 0,32,64,96
constexpr int IR_UD = 128;         // update-arrival stripes at 128,160,192,224
constexpr int IR_E0 = 1024;        // unsigned elist0[992] (static step-0 list)

__device__ __forceinline__ float sigf(float x) { return 1.f / (1.f + expf(-x)); }

// device-scope (L2-bypassing) helpers — producers push payloads to LLC
__device__ __forceinline__ int ld_sc(const int* p) {
    return __hip_atomic_load(p, __ATOMIC_RELAXED, __HIP_MEMORY_SCOPE_AGENT);
}
__device__ __forceinline__ void st_sc64(void* p, u64 v) {
    __hip_atomic_store((u64*)p, v, __ATOMIC_RELAXED, __HIP_MEMORY_SCOPE_AGENT);
}
__device__ __forceinline__ u64 packf2(float a, float b) {
    return (u64)__float_as_uint(a) | ((u64)__float_as_uint(b) << 32);
}
// entry pack: bits0-4 batch, 5-9 pair-slot (pnh/pnc space), 10-15 left h, 16-21 right h
__device__ __forceinline__ unsigned pack_e(int b, int slot, int l, int r) {
    return (unsigned)b | ((unsigned)slot << 5) | ((unsigned)l << 10) | ((unsigned)r << 16);
}

// ---------------- init: step-0 list, zero slot, counters ----------------
__global__ __launch_bounds__(256) void init_kernel(
    int* __restrict__ ireg,
    _Float16* __restrict__ hHi, _Float16* __restrict__ hLo, float* __restrict__ cSt)
{
    const int blk = blockIdx.x, tid = threadIdx.x;
    if (blk < 32) {
        if (tid < 31)
            ireg[IR_E0 + tid * 32 + blk] = (int)pack_e(blk, tid, tid, tid + 1);
    } else if (blk == 32) {
        const size_t zb = (size_t)HSLOT_Z * NB * NHID;
        for (int i = tid; i < NB * NHID; i += 256) {
            hHi[zb + i] = (_Float16)0.f;
            hLo[zb + i] = (_Float16)0.f;
            cSt[zb + i] = 0.f;
        }
    } else {
        if (tid == 0 || tid == 1) {}   // nothing
        for (int i = tid; i < 1024; i += 256) ireg[i] = 0;   // gd/ud stripes
    }
}

// ---------------- W_comp -> transposed split fp16 planes ----------------
__global__ __launch_bounds__(256) void wsplit_kernel(
    const float* __restrict__ W, _Float16* __restrict__ Wth, _Float16* __restrict__ Wtl)
{
    __shared__ float t[32][33];
    const int n0 = blockIdx.x * 32, k0 = blockIdx.y * 32;
    const int tid = threadIdx.x;
    const int c = tid & 31, r8 = tid >> 5;
#pragma unroll
    for (int p = 0; p < 4; ++p) {
        int r = p * 8 + r8;
        t[r][c] = W[(size_t)(k0 + r) * NC5 + n0 + c];
    }
    __syncthreads();
    const int nl = tid >> 3, k4 = (tid & 7) * 4;
    half4 vh, vl;
#pragma unroll
    for (int i = 0; i < 4; ++i) {
        float v = t[k4 + i][nl];
        _Float16 hh = (_Float16)v;
        vh[i] = hh;
        vl[i] = (_Float16)((v - (float)hh) * 2048.f);
    }
    size_t o = (size_t)(n0 + nl) * 1024 + k0 + k4;
    *(half4*)&Wth[o] = vh;
    *(half4*)&Wtl[o] = vl;
}

// ---------------- word GEMM: leaves -> state slots 0..31 ----------------
__global__ __launch_bounds__(256) void word_gemm64(
    const float* __restrict__ A, const float* __restrict__ W,
    const float* __restrict__ bias,
    _Float16* __restrict__ hi0, _Float16* __restrict__ lo0,
    float* __restrict__ cst, float* __restrict__ out)
{
    const int m0 = blockIdx.x * 64;
    const int n0 = blockIdx.y * 64;
    const int tid = threadIdx.x;
    const int tx = tid & 15, ty = tid >> 4;
    __shared__ float As[16][64];
    __shared__ float Bs[16][64];
    float acc[4][4];
#pragma unroll
    for (int i = 0; i < 4; ++i)
#pragma unroll
        for (int j = 0; j < 4; ++j) acc[i][j] = 0.f;

    for (int kt = 0; kt < ND; kt += 16) {
        {
            int row = tid >> 2, kq = tid & 3;
            float4 v = *(const float4*)(A + (size_t)(m0 + row) * ND + kt + kq * 4);
            As[kq * 4 + 0][row] = v.x;
            As[kq * 4 + 1][row] = v.y;
            As[kq * 4 + 2][row] = v.z;
            As[kq * 4 + 3][row] = v.w;
            int kr = tid >> 4, nq = tid & 15;
            float4 vb = *(const float4*)(W + (size_t)(kt + kr) * 1024 + n0 + nq * 4);
            *(float4*)&Bs[kr][nq * 4] = vb;
        }
        __syncthreads();
#pragma unroll
        for (int kk = 0; kk < 16; ++kk) {
            float a0 = As[kk][ty * 4 + 0], a1 = As[kk][ty * 4 + 1];
            float a2 = As[kk][ty * 4 + 2], a3 = As[kk][ty * 4 + 3];
            float4 bv = *(float4*)&Bs[kk][tx * 4];
            acc[0][0] = fmaf(a0, bv.x, acc[0][0]); acc[0][1] = fmaf(a0, bv.y, acc[0][1]);
            acc[0][2] = fmaf(a0, bv.z, acc[0][2]); acc[0][3] = fmaf(a0, bv.w, acc[0][3]);
            acc[1][0] = fmaf(a1, bv.x, acc[1][0]); acc[1][1] = fmaf(a1, bv.y, acc[1][1]);
            acc[1][2] = fmaf(a1, bv.z, acc[1][2]); acc[1][3] = fmaf(a1, bv.w, acc[1][3]);
            acc[2][0] = fmaf(a2, bv.x, acc[2][0]); acc[2][1] = fmaf(a2, bv.y, acc[2][1]);
            acc[2][2] = fmaf(a2, bv.z, acc[2][2]); acc[2][3] = fmaf(a2, bv.w, acc[2][3]);
            acc[3][0] = fmaf(a3, bv.x, acc[3][0]); acc[3][1] = fmaf(a3, bv.y, acc[3][1]);
            acc[3][2] = fmaf(a3, bv.z, acc[3][2]); acc[3][3] = fmaf(a3, bv.w, acc[3][3]);
        }
        __syncthreads();
    }
    float* nodes = out + 2 * BH;
#pragma unroll
    for (int i = 0; i < 4; ++i) {
        int r = m0 + ty * 4 + i;
        int b = r >> 5, l = r & 31;
#pragma unroll
        for (int jn = 0; jn < 4; ++jn) {
            int n = n0 + tx * 4 + jn;
            float v = acc[i][jn] + bias[n];
            if (n < NHID) {
                size_t si = ((size_t)l * NB + b) * NHID + n;
                _Float16 hh = (_Float16)v;
                hi0[si] = hh;
                lo0[si] = (_Float16)((v - (float)hh) * 2048.f);
                nodes[((size_t)b * 63 + l) * NHID + n] = v;
            } else {
                cst[((size_t)l * NB + b) * NHID + (n - NHID)] = v;
            }
        }
    }
}

// ---------------- persistent kernel ----------------
// 160 blocks. Step 0: all blocks GEMM (col nt%80, parity nt/80). Then blocks
// 0..79 = GEMM role (steps 1..30), 80..111 = update role (batch nt-80),
// 112..159 retire. Sync: striped cumulative counters gd (GEMM->update) and
// ud (update->GEMM). All cross-role payloads are write-once and sc-published;
// consumers use plain cached loads (first touch after publish -> LLC-fresh).
__global__ __launch_bounds__(256, 1) void tree_loop(
    _Float16* __restrict__ hHi, _Float16* __restrict__ hLo,
    const _Float16* __restrict__ Wth, const _Float16* __restrict__ Wtl,
    float* __restrict__ graw, const float* __restrict__ bias,
    const float* __restrict__ q, const int* __restrict__ len,
    float* __restrict__ pnh, float* __restrict__ pnc, float* __restrict__ cSt,
    u64* __restrict__ elist, int* __restrict__ ireg, float* __restrict__ out)
{
    const int nt = blockIdx.x;
    const int tid = threadIdx.x;
    const int col = nt % NGEMM;
    const int kw = tid >> 6, lane = tid & 63;
    const int l5 = lane >> 5, ln = lane & 31;

    int* gd = ireg + IR_GD;
    int* ud = ireg + IR_UD;

    __shared__ float red[4][32][32];
    __shared__ unsigned s_entry[64];
    __shared__ int s_pidx[32], s_hidx[32], s_cidx[32];
    __shared__ float s_plog[32];
    __shared__ int s_k, s_prevk;

    // B panel preload: 32 cols x 256 K per wave, hi+lo -> 128 VGPRs, once.
    const _Float16* bHiP = Wth + (size_t)(col * 32 + ln) * 1024 + (kw << 8) + l5 * 8;
    const _Float16* bLoP = Wtl + (size_t)(col * 32 + ln) * 1024 + (kw << 8) + l5 * 8;
    half8 Bh[16], Bl[16];
#pragma unroll
    for (int ks = 0; ks < 16; ++ks) {
        Bh[ks] = *(const half8*)(bHiP + ks * 16);
        Bl[ks] = *(const half8*)(bLoP + ks * 16);
    }

    // one 32-row tile: entries se[0..31], graw rows growbase+row (write-once)
    auto gemm_tile = [&](const unsigned* se, int growbase) {
        {
            const unsigned e = se[ln];
            const int db = e & 31;
            const int lsl = (e >> 10) & 63, rsl = (e >> 16) & 63;
            const int hs = (kw < 2) ? lsl : rsl;
            const int koff = ((kw & 1) << 8) + l5 * 8;
            const _Float16* aHiP = hHi + ((size_t)hs * NB + db) * NHID + koff;
            const _Float16* aLoP = hLo + ((size_t)hs * NB + db) * NHID + koff;
            f32x16 acc1 = (f32x16)0.f, acc2 = (f32x16)0.f;
#pragma unroll
            for (int ks = 0; ks < 16; ++ks) {
                half8 Ah = *(const half8*)(aHiP + ks * 16);
                half8 Al = *(const half8*)(aLoP + ks * 16);
                acc1 = __builtin_amdgcn_mfma_f32_32x32x16_f16(Ah, Bh[ks], acc1, 0, 0, 0);
                acc2 = __builtin_amdgcn_mfma_f32_32x32x16_f16(Ah, Bl[ks], acc2, 0, 0, 0);
                acc2 = __builtin_amdgcn_mfma_f32_32x32x16_f16(Al, Bh[ks], acc2, 0, 0, 0);
            }
            // C/D: col=lane&31, row=(a&3)+8*(a>>2)+4*(lane>>5)
#pragma unroll
            for (int a = 0; a < 16; ++a) {
                int row = (a & 3) + 8 * (a >> 2) + 4 * l5;
                red[kw][row][ln] = acc1[a] + acc2[a] * INV2048;
            }
        }
        __syncthreads();
        {
            const int row = tid >> 3, c0 = (tid & 7) * 4;
            float4 s;
            s.x = (red[0][row][c0+0] + red[1][row][c0+0]) + (red[2][row][c0+0] + red[3][row][c0+0]);
            s.y = (red[0][row][c0+1] + red[1][row][c0+1]) + (red[2][row][c0+1] + red[3][row][c0+1]);
            s.z = (red[0][row][c0+2] + red[1][row][c0+2]) + (red[2][row][c0+2] + red[3][row][c0+2]);
            s.w = (red[0][row][c0+3] + red[1][row][c0+3]) + (red[2][row][c0+3] + red[3][row][c0+3]);
            float* gp = &graw[(size_t)(growbase + row) * NC5 + col * 32 + c0];
            st_sc64(gp,     packf2(s.x, s.y));   // publish to LLC
            st_sc64(gp + 2, packf2(s.z, s.w));
        }
        __syncthreads();
    };

    // ---- step 0: all 160 blocks GEMM (31 tiles, split by parity) ----
    {
        const int par = nt / NGEMM;        // 0 or 1
        for (int mt = par; mt < 31; mt += 2) {
            if (tid < 32) s_entry[tid] = (unsigned)ireg[IR_E0 + mt * 32 + tid];
            __syncthreads();
            gemm_tile(s_entry, mt * 32);
        }
        // trailing __syncthreads in gemm_tile drained all stores
        if (tid == 0)
            __hip_atomic_fetch_add(&gd[(nt & 3) * 32], 1, __ATOMIC_RELAXED,
                                   __HIP_MEMORY_SCOPE_AGENT);
    }
    if (nt >= 112) return;

    if (nt < NGEMM) {
        // ---- GEMM role: steps 1..30 ----
        for (int step = 1; step < NSTEPS; ++step) {
            if (tid < 4) {
                const int tgt = 8 * step;
                while (ld_sc(&ud[tid * 32]) < tgt) __builtin_amdgcn_s_sleep(2);
            }
            __syncthreads();
            if (tid < 64)      // plain cached load: step-indexed, first touch
                s_entry[tid] = (unsigned)elist[step * 64 + tid];
            __syncthreads();
            const int base = NROW0 + (step - 1) * 64;
            gemm_tile(s_entry, base);
            gemm_tile(s_entry + 32, base + 32);
            if (tid == 0)
                __hip_atomic_fetch_add(&gd[(nt & 3) * 32], 1, __ATOMIC_RELAXED,
                                       __HIP_MEMORY_SCOPE_AGENT);
        }
        return;
    }

    // ---- UPDATE role: batch b = nt - 80, steps 0..30 ----
    {
        const int b = nt - NGEMM;
        const int lenb = len[b];
        if (tid < 32) { s_pidx[tid] = min(tid, 30); s_hidx[tid] = tid; s_cidx[tid] = tid; }
        if (tid == 0) s_prevk = -1;
        __syncthreads();

        for (int step = 0; step < NSTEPS; ++step) {
            if (tid < 4) {
                const int tgt = 40 + 20 * step;
                while (ld_sc(&gd[tid * 32]) < tgt) __builtin_amdgcn_s_sleep(2);
            }
            __syncthreads();

            const int pk = s_prevk;
            int nf;
            if (step == 0) nf = 31; else if (pk < 0) nf = 0; else nf = (pk >= 1) ? 2 : 1;

            // Phase A: fresh pairs, one per wave; graw via PLAIN cached float4
            for (int f = kw; f < nf; f += 4) {
                const int j = (step == 0) ? f : (pk - (nf - 1) + f);
                const int slot = s_pidx[j];
                const int lc = s_cidx[j], rc2 = s_cidx[j + 1];
                const int grow = (step == 0) ? (j * 32 + b)
                                             : (NROW0 + (step - 1) * 64 + 2 * b + (f + 2 - nf));
                const float* gr  = graw + (size_t)grow * NC5;
                const float* clp = cSt + ((size_t)lc * NB + b) * NHID;
                const float* crp = cSt + ((size_t)rc2 * NB + b) * NHID;
                float lpart = 0.f;
#pragma unroll
                for (int i = 0; i < 2; ++i) {
                    const int h = 4 * lane + 256 * i;
                    float4 g0 = *(const float4*)(gr + h);
                    float4 g1 = *(const float4*)(gr + 512 + h);
                    float4 g2 = *(const float4*)(gr + 1024 + h);
                    float4 g3 = *(const float4*)(gr + 1536 + h);
                    float4 g4 = *(const float4*)(gr + 2048 + h);
                    const float4 b0 = *(const float4*)(bias + h);
                    const float4 b1 = *(const float4*)(bias + 512 + h);
                    const float4 b2 = *(const float4*)(bias + 1024 + h);
                    const float4 b3 = *(const float4*)(bias + 1536 + h);
                    const float4 b4 = *(const float4*)(bias + 2048 + h);
                    const float4 cl4 = *(const float4*)(clp + h);
                    const float4 cr4 = *(const float4*)(crp + h);
                    const float4 q4  = *(const float4*)(q + h);
                    float4 hv, cv;
#define CELL(e) { \
                    float c = cl4.e * sigf(g1.e + b1.e + 1.f) + cr4.e * sigf(g2.e + b2.e + 1.f) \
                            + tanhf(g3.e + b3.e) * sigf(g0.e + b0.e); \
                    float hh = sigf(g4.e + b4.e) * tanhf(c); \
                    cv.e = c; hv.e = hh; lpart = fmaf(hh, q4.e, lpart); }
                    CELL(x) CELL(y) CELL(z) CELL(w)
#undef CELL
                    const size_t po = ((size_t)slot * NB + b) * NHID + h;
                    *(float4*)(pnh + po) = hv;
                    *(float4*)(pnc + po) = cv;
                }
#pragma unroll
                for (int off = 32; off > 0; off >>= 1) lpart += __shfl_down(lpart, off);
                if (lane == 0) s_plog[slot] = lpart;
            }
            __syncthreads();

            // Phase B: argmax over j < actb (first-index tie-break)
            const int actb = lenb - 1 - step;
            const int merge = actb >= 1;
            if (tid < 64) {
                float v = -1e30f;
                int idx = tid;
                if (tid < actb && tid < 31) v = s_plog[s_pidx[tid]];
#pragma unroll
                for (int off = 32; off > 0; off >>= 1) {
                    float ov = __shfl_down(v, off);
                    int   oi = __shfl_down(idx, off);
                    if (ov > v || (ov == v && oi < idx)) { v = ov; idx = oi; }
                }
                if (tid == 0) s_k = idx;
            }
            __syncthreads();
            const int k = s_k;
            const int last = (step == NSTEPS - 1);
            const int NSLOT = 33 + step;

            // Phase C: node output, fresh h write (sc), final hf/cf
            float* noderow = out + 2 * BH + ((size_t)b * 63 + 32 + step) * NHID;
            if (merge) {
                const int kslot = s_pidx[k];
                const int csl = s_cidx[k];
                if (tid < 128) {
                    const int h0 = tid * 4;
                    const size_t pb = ((size_t)kslot * NB + b) * NHID + h0;
                    float4 x4 = *(const float4*)&pnh[pb];
                    float4 c4 = *(const float4*)&pnc[pb];
                    half4 hv, lv;
#pragma unroll
                    for (int i = 0; i < 4; ++i) {
                        float x = (&x4.x)[i];
                        _Float16 hh = (_Float16)x;
                        hv[i] = hh;
                        lv[i] = (_Float16)((x - (float)hh) * 2048.f);
                    }
                    const size_t so = ((size_t)NSLOT * NB + b) * NHID + h0;
                    st_sc64(&hHi[so], __builtin_bit_cast(u64, hv));
                    st_sc64(&hLo[so], __builtin_bit_cast(u64, lv));
                    *(float4*)&cSt[((size_t)csl * NB + b) * NHID + h0] = c4;
                    *(float4*)&noderow[h0] = x4;
                    if (last) {
                        *(float4*)&out[b * NHID + h0] = x4;
                        *(float4*)&out[BH + b * NHID + h0] = c4;
                    }
                }
            } else {
                const int s0p = s_pidx[0], s0h = s_hidx[0], s0c = s_cidx[0];
                if (tid < 128) {
                    const int h0 = tid * 4;
                    if (!last) {
                        *(float4*)&noderow[h0] =
                            *(const float4*)&pnh[((size_t)s0p * NB + b) * NHID + h0];
                    } else {
                        const size_t so = ((size_t)s0h * NB + b) * NHID + h0;
                        half4 hv = *(const half4*)&hHi[so];   // write-once, LLC-fresh
                        half4 lv = *(const half4*)&hLo[so];
                        float4 x4;
#pragma unroll
                        for (int i = 0; i < 4; ++i)
                            (&x4.x)[i] = (float)hv[i] + (float)lv[i] * INV2048;
                        *(float4*)&noderow[h0] = x4;
                        *(float4*)&out[b * NHID + h0] = x4;
                        *(float4*)&out[BH + b * NHID + h0] =
                            *(const float4*)&cSt[((size_t)s0c * NB + b) * NHID + h0];
                    }
                }
            }
            __syncthreads();   // drains ALL waves' stores (incl. sc h-stores)

            // Phase D: publish entries for step+1 (sc), bump ud, shift bookkeeping
            if (tid == 0) {
                const unsigned dummy = pack_e(b, 31, HSLOT_Z, HSLOT_Z);
                if (merge) {
                    unsigned e1 = pack_e(b, s_pidx[k], NSLOT,
                                         (k + 2 <= 31) ? s_hidx[k + 2] : HSLOT_Z);
                    unsigned e0 = (k >= 1)
                        ? pack_e(b, s_pidx[k - 1], s_hidx[k - 1], NSLOT) : dummy;
                    if (!last) {
                        st_sc64(&elist[(step + 1) * 64 + 2 * b],     (u64)e0);
                        st_sc64(&elist[(step + 1) * 64 + 2 * b + 1], (u64)e1);
                        asm volatile("s_waitcnt vmcnt(0)" ::: "memory");
                        __hip_atomic_fetch_add(&ud[(b & 3) * 32], 1, __ATOMIC_RELAXED,
                                               __HIP_MEMORY_SCOPE_AGENT);
                    }
                    const int recycP = s_pidx[k + 1];
                    for (int j2 = k + 1; j2 <= 29; ++j2) s_pidx[j2] = s_pidx[j2 + 1];
                    if (k < 30) s_pidx[30] = recycP;
                    s_hidx[k] = NSLOT;
                    for (int pp = k + 1; pp <= 30; ++pp) s_hidx[pp] = s_hidx[pp + 1];
                    s_hidx[31] = HSLOT_Z;
                    for (int pp = k + 1; pp <= 30; ++pp) s_cidx[pp] = s_cidx[pp + 1];
                    s_cidx[31] = HSLOT_Z;
                    s_prevk = k;
                } else {
                    if (!last) {
                        st_sc64(&elist[(step + 1) * 64 + 2 * b],     (u64)dummy);
                        st_sc64(&elist[(step + 1) * 64 + 2 * b + 1], (u64)dummy);
                        asm volatile("s_waitcnt vmcnt(0)" ::: "memory");
                        __hip_atomic_fetch_add(&ud[(b & 3) * 32], 1, __ATOMIC_RELAXED,
                                               __HIP_MEMORY_SCOPE_AGENT);
                    }
                    s_prevk = -1;
                }
            }
        }
    }
}

extern "C" void kernel_launch(void* const* d_in, const int* in_sizes, int n_in,
                              void* d_out, int out_size, void* d_ws, size_t ws_size,
                              hipStream_t stream) {
    const float* inp    = (const float*)d_in[0];
    const int*   length = (const int*)d_in[1];
    const float* W_word = (const float*)d_in[2];
    const float* b_word = (const float*)d_in[3];
    const float* W_comp = (const float*)d_in[4];
    const float* b_comp = (const float*)d_in[5];
    const float* q      = (const float*)d_in[6];
    float* out = (float*)d_out;
    float* ws  = (float*)d_ws;

    float*     graw = ws + OFF_GRAW;
    float*     pnh  = ws + OFF_PNH;
    float*     pnc  = ws + OFF_PNC;
    float*     cSt  = ws + OFF_CST;
    _Float16*  hHi  = (_Float16*)(ws + OFF_HHI);
    _Float16*  hLo  = (_Float16*)(ws + OFF_HLO);
    _Float16*  Wth  = (_Float16*)(ws + OFF_WTH);
    _Float16*  Wtl  = (_Float16*)(ws + OFF_WTL);
    int*       ireg = (int*)(ws + OFF_INT);
    u64*       elist = (u64*)(ws + OFF_LIST);

    init_kernel<<<34, 256, 0, stream>>>(ireg, hHi, hLo, cSt);
    wsplit_kernel<<<dim3(NC5 / 32, 1024 / 32), 256, 0, stream>>>(W_comp, Wth, Wtl);
    word_gemm64<<<dim3(16, 16), 256, 0, stream>>>(inp, W_word, b_word,
                                                  hHi, hLo, cSt, out);
    tree_loop<<<NBLK, 256, 0, stream>>>(hHi, hLo, Wth, Wtl, graw, b_comp, q, length,
                                        pnh, pnc, cSt, elist, ireg, out);
}